// Round 10
// baseline (131.853 us; speedup 1.0000x reference)
//
#include <hip/hip_runtime.h>

#define NLOG2E -1.44269504088896340736f

typedef float f32x2 __attribute__((ext_vector_type(2)));
typedef float f32x4 __attribute__((ext_vector_type(4)));

// K1 (1 thread): fold weight algebra into 69 floats in d_ws.
// K2: PERSISTENT grid-stride kernel: 2048 blocks (8 blocks/CU -> 32 resident
//     waves/CU, the max), 4 rows/iter, 4 iters/thread, prefetch-by-one.
//     Packed f32x2 math (v_pk_fma_f32 et al.), constants via s_load->SGPR
//     amortized over all iterations. __launch_bounds__(256,8) caps VGPR at 64
//     so full occupancy is achievable. Non-temporal out stores (ext-vector
//     type, NOT HIP float4 — the builtin rejects class types).
//
// ws layout (floats): [0:8)=uw0 [8:16)=uw1 [16:24)=ub [24:56)=w2f
//                     [56:60)=b2 [60:64)=ncl2 [64:68)=aw2 [68]=bb3

__global__ void prefold_kernel(
    const float* __restrict__ W1, const float* __restrict__ b1,
    const float* __restrict__ a1, const float* __restrict__ c1,
    const float* __restrict__ W2, const float* __restrict__ b2,
    const float* __restrict__ a2, const float* __restrict__ c2,
    const float* __restrict__ W3, const float* __restrict__ b3,
    float* __restrict__ C)
{
    if (threadIdx.x == 0 && blockIdx.x == 0) {
        for (int j = 0; j < 8; ++j) {
            float ncl = c1[j] * NLOG2E;
            C[j]      = W1[j]     * ncl;
            C[8 + j]  = W1[8 + j] * ncl;
            C[16 + j] = b1[j]     * ncl;
            float k1 = a1[j] / ncl;
            for (int k = 0; k < 4; ++k)
                C[24 + j * 4 + k] = W2[j * 4 + k] * k1;
        }
        for (int k = 0; k < 4; ++k) {
            C[56 + k] = b2[k];
            C[60 + k] = c2[k] * NLOG2E;
            C[64 + k] = a2[k] * W3[k];
        }
        C[68] = b3[0];
    }
}

__global__ __launch_bounds__(256, 8) void PlaygroundModel_66365834658304_kernel(
    const float* __restrict__ x, const float* __restrict__ C,
    float* __restrict__ out, int units, int rows, int T)
{
    const f32x2* Cp = (const f32x2*)C;
    // uw0 pairs: Cp[0..3]  uw1: Cp[4..7]  ub: Cp[8..11]
    // w2f pairs: Cp[12 + j*2 + kp]  b2: Cp[28..29]  ncl2: Cp[30..31]
    // aw2: Cp[32..33]  bb3: C[68]
    float bb3 = C[68];

    int tid = blockIdx.x * blockDim.x + threadIdx.x;
    const f32x4* x4 = (const f32x4*)x;
    f32x4* o4 = (f32x4*)out;

    int u = tid;
    f32x4 n0, n1;
    if (u < units) {                       // prime
        n0 = x4[(size_t)u * 2 + 0];
        n1 = x4[(size_t)u * 2 + 1];
    }
    while (u < units) {
        f32x4 c0 = n0, c1 = n1;
        int nu = u + T;
        if (nu < units) {                  // prefetch next iteration
            n0 = x4[(size_t)nu * 2 + 0];
            n1 = x4[(size_t)nu * 2 + 1];
        }

        float X0[4] = {c0.x, c0.z, c1.x, c1.z};
        float X1[4] = {c0.y, c0.w, c1.y, c1.w};

        // stage 1: u-values, 4 rows x 4 j-pairs of pk_fma
        f32x2 uv[4][4];
#pragma unroll
        for (int r = 0; r < 4; ++r) {
            f32x2 x0b = {X0[r], X0[r]};
            f32x2 x1b = {X1[r], X1[r]};
#pragma unroll
            for (int p = 0; p < 4; ++p)
                uv[r][p] = __builtin_elementwise_fma(
                               x0b, Cp[p],
                               __builtin_elementwise_fma(x1b, Cp[4 + p],
                                                         Cp[8 + p]));
        }

        // stage 2: h_eff = u * rcp(1 + exp2(u)); trans scalar, rest packed
#pragma unroll
        for (int r = 0; r < 4; ++r)
#pragma unroll
            for (int p = 0; p < 4; ++p) {
                f32x2 e;
                e[0] = __builtin_amdgcn_exp2f(uv[r][p][0]);
                e[1] = __builtin_amdgcn_exp2f(uv[r][p][1]);
                f32x2 d = e + 1.0f;
                f32x2 s;
                s[0] = __builtin_amdgcn_rcpf(d[0]);
                s[1] = __builtin_amdgcn_rcpf(d[1]);
                uv[r][p] *= s;             // h_eff in place
            }

        // stage 3: layer-2 dot-8, two k-pair accumulators per row
        float res[4];
#pragma unroll
        for (int r = 0; r < 4; ++r) {
            f32x2 ta = Cp[28], tb = Cp[29];
#pragma unroll
            for (int j = 0; j < 8; ++j) {
                float hj = uv[r][j >> 1][j & 1];
                f32x2 hb = {hj, hj};
                ta = __builtin_elementwise_fma(hb, Cp[12 + j * 2 + 0], ta);
                tb = __builtin_elementwise_fma(hb, Cp[12 + j * 2 + 1], tb);
            }
            // stage 4: second activation + final reduce
            f32x2 u2a = Cp[30] * ta;
            f32x2 u2b = Cp[31] * tb;
            f32x2 ea, eb;
            ea[0] = __builtin_amdgcn_exp2f(u2a[0]);
            ea[1] = __builtin_amdgcn_exp2f(u2a[1]);
            eb[0] = __builtin_amdgcn_exp2f(u2b[0]);
            eb[1] = __builtin_amdgcn_exp2f(u2b[1]);
            f32x2 da = ea + 1.0f, db = eb + 1.0f;
            f32x2 sa, sb;
            sa[0] = __builtin_amdgcn_rcpf(da[0]);
            sa[1] = __builtin_amdgcn_rcpf(da[1]);
            sb[0] = __builtin_amdgcn_rcpf(db[0]);
            sb[1] = __builtin_amdgcn_rcpf(db[1]);
            f32x2 pa = ta * sa;
            f32x2 pb = tb * sb;
            f32x2 acc = {bb3, 0.0f};
            acc = __builtin_elementwise_fma(pa, Cp[32], acc);
            acc = __builtin_elementwise_fma(pb, Cp[33], acc);
            res[r] = acc[0] + acc[1];
        }
        f32x4 ov = {res[0], res[1], res[2], res[3]};
        __builtin_nontemporal_store(ov, &o4[u]);
        u = nu;
    }

    // scalar tail for rows % 4 != 0 (not hit for B = 8388608)
    if (tid == 0) {
        const float* uw0  = C;
        const float* uw1  = C + 8;
        const float* ub   = C + 16;
        const float* w2f  = C + 24;
        const float* bb2  = C + 56;
        const float* ncl2 = C + 60;
        const float* aw2  = C + 64;
        for (long long rr = (long long)units * 4; rr < rows; ++rr) {
            float x0 = x[rr * 2 + 0], x1 = x[rr * 2 + 1];
            float h[8];
#pragma unroll
            for (int j = 0; j < 8; ++j) {
                float uu = fmaf(x0, uw0[j], fmaf(x1, uw1[j], ub[j]));
                float s  = __builtin_amdgcn_rcpf(
                               1.0f + __builtin_amdgcn_exp2f(uu));
                h[j] = uu * s;
            }
            float o = bb3;
#pragma unroll
            for (int k = 0; k < 4; ++k) {
                float t = bb2[k];
#pragma unroll
                for (int j = 0; j < 8; ++j) t = fmaf(h[j], w2f[j * 4 + k], t);
                float u2 = ncl2[k] * t;
                float sg = __builtin_amdgcn_rcpf(
                               1.0f + __builtin_amdgcn_exp2f(u2));
                o = fmaf(t * sg, aw2[k], o);
            }
            out[rr] = o;
        }
    }
}

extern "C" void kernel_launch(void* const* d_in, const int* in_sizes, int n_in,
                              void* d_out, int out_size, void* d_ws, size_t ws_size,
                              hipStream_t stream) {
    const float* x  = (const float*)d_in[0];
    const float* W1 = (const float*)d_in[1];
    const float* b1 = (const float*)d_in[2];
    const float* a1 = (const float*)d_in[3];
    const float* c1 = (const float*)d_in[4];
    const float* W2 = (const float*)d_in[5];
    const float* b2 = (const float*)d_in[6];
    const float* a2 = (const float*)d_in[7];
    const float* c2 = (const float*)d_in[8];
    const float* W3 = (const float*)d_in[9];
    const float* b3 = (const float*)d_in[10];
    float* out = (float*)d_out;
    float* C   = (float*)d_ws;

    prefold_kernel<<<1, 64, 0, stream>>>(W1, b1, a1, c1, W2, b2, a2, c2,
                                         W3, b3, C);

    int rows  = in_sizes[0] / 2;
    int units = rows / 4;                  // 4 rows per unit
    int block = 256;
    int grid  = 2048;                      // 8 blocks/CU -> 32 waves/CU resident
    int T     = grid * block;              // 524288 threads, 4 iters each

    PlaygroundModel_66365834658304_kernel<<<grid, block, 0, stream>>>(
        x, C, out, units, rows, T);
}

// Round 11
// 129.640 us; speedup vs baseline: 1.0171x; 1.0171x over previous
//
#include <hip/hip_runtime.h>

#define NLOG2E -1.44269504088896340736f

typedef float f32x2 __attribute__((ext_vector_type(2)));
typedef float f32x4 __attribute__((ext_vector_type(4)));

// K1 (1 thread): fold weight algebra into 69 floats in d_ws.
// K2: one-shot, 4 rows/thread, packed f32x2 math. Sigmoid reciprocals are
//     batch-inverted with packed product trees: 8-way per row for layer 1
//     (1 rcp instead of 8), 4-way for layer 2 (1 instead of 4). Trans instrs
//     per 4-row iter: 96 -> 50. exp2 inputs clamped (15 for the 8-way tree,
//     30 for the 4-way) so denominator products cannot overflow f32.
//
// ws layout (floats): [0:8)=uw0 [8:16)=uw1 [16:24)=ub [24:56)=w2f
//                     [56:60)=b2 [60:64)=ncl2 [64:68)=aw2 [68]=bb3

__global__ void prefold_kernel(
    const float* __restrict__ W1, const float* __restrict__ b1,
    const float* __restrict__ a1, const float* __restrict__ c1,
    const float* __restrict__ W2, const float* __restrict__ b2,
    const float* __restrict__ a2, const float* __restrict__ c2,
    const float* __restrict__ W3, const float* __restrict__ b3,
    float* __restrict__ C)
{
    if (threadIdx.x == 0 && blockIdx.x == 0) {
        for (int j = 0; j < 8; ++j) {
            float ncl = c1[j] * NLOG2E;
            C[j]      = W1[j]     * ncl;
            C[8 + j]  = W1[8 + j] * ncl;
            C[16 + j] = b1[j]     * ncl;
            float k1 = a1[j] / ncl;
            for (int k = 0; k < 4; ++k)
                C[24 + j * 4 + k] = W2[j * 4 + k] * k1;
        }
        for (int k = 0; k < 4; ++k) {
            C[56 + k] = b2[k];
            C[60 + k] = c2[k] * NLOG2E;
            C[64 + k] = a2[k] * W3[k];
        }
        C[68] = b3[0];
    }
}

__global__ __launch_bounds__(256, 4) void PlaygroundModel_66365834658304_kernel(
    const float* __restrict__ x, const float* __restrict__ C,
    float* __restrict__ out, int rows)
{
    const f32x2* Cp = (const f32x2*)C;
    // uw0 pairs: Cp[0..3]  uw1: Cp[4..7]  ub: Cp[8..11]
    // w2f pairs: Cp[12 + j*2 + kp]  b2: Cp[28..29]  ncl2: Cp[30..31]
    // aw2: Cp[32..33]  bb3: C[68]
    float bb3 = C[68];
    const f32x2 lim15 = {15.0f, 15.0f};
    const f32x2 lim30 = {30.0f, 30.0f};

    int tid = blockIdx.x * blockDim.x + threadIdx.x;
    long long base = (long long)tid * 4;

    if (base + 3 < rows) {
        const f32x4* x4 = (const f32x4*)x;
        f32x4 p0 = x4[(size_t)tid * 2 + 0];
        f32x4 p1 = x4[(size_t)tid * 2 + 1];
        float X0[4] = {p0.x, p0.z, p1.x, p1.z};
        float X1[4] = {p0.y, p0.w, p1.y, p1.w};

        // stage 1: u-values, 4 rows x 4 j-pairs of pk_fma
        f32x2 uv[4][4];
#pragma unroll
        for (int r = 0; r < 4; ++r) {
            f32x2 x0b = {X0[r], X0[r]};
            f32x2 x1b = {X1[r], X1[r]};
#pragma unroll
            for (int p = 0; p < 4; ++p)
                uv[r][p] = __builtin_elementwise_fma(
                               x0b, Cp[p],
                               __builtin_elementwise_fma(x1b, Cp[4 + p],
                                                         Cp[8 + p]));
        }

        // stage 2: h_eff = u * (1/(1+exp2(u))); 8-way batched inverse per row
#pragma unroll
        for (int r = 0; r < 4; ++r) {
            f32x2 P[4];
#pragma unroll
            for (int p = 0; p < 4; ++p) {
                f32x2 uc = __builtin_elementwise_min(uv[r][p], lim15);
                f32x2 e;
                e[0] = __builtin_amdgcn_exp2f(uc[0]);
                e[1] = __builtin_amdgcn_exp2f(uc[1]);
                P[p] = e + 1.0f;          // d in [1, 2^15+1]
            }
            f32x2 M01 = P[0] * P[1];      // {d0d2, d1d3}
            f32x2 M23 = P[2] * P[3];      // {d4d6, d5d7}
            f32x2 M   = M01 * M23;        // {d0d2d4d6, d1d3d5d7}
            float R   = __builtin_amdgcn_rcpf(M[0] * M[1]);
            f32x2 RM; RM[0] = M[1] * R; RM[1] = M[0] * R;
            f32x2 iM01 = RM * M23;        // {1/(d0d2), 1/(d1d3)}
            f32x2 iM23 = RM * M01;        // {1/(d4d6), 1/(d5d7)}
            uv[r][0] *= iM01 * P[1];      // {1/d0, 1/d1}
            uv[r][1] *= iM01 * P[0];      // {1/d2, 1/d3}
            uv[r][2] *= iM23 * P[3];      // {1/d4, 1/d5}
            uv[r][3] *= iM23 * P[2];      // {1/d6, 1/d7}
        }

        // stage 3+4: layer-2 dot-8, 4-way batched second activation, reduce
        float res[4];
#pragma unroll
        for (int r = 0; r < 4; ++r) {
            f32x2 ta = Cp[28], tb = Cp[29];
#pragma unroll
            for (int j = 0; j < 8; ++j) {
                float hj = uv[r][j >> 1][j & 1];
                f32x2 hb = {hj, hj};
                ta = __builtin_elementwise_fma(hb, Cp[12 + j * 2 + 0], ta);
                tb = __builtin_elementwise_fma(hb, Cp[12 + j * 2 + 1], tb);
            }
            f32x2 u2a = __builtin_elementwise_min(Cp[30] * ta, lim30);
            f32x2 u2b = __builtin_elementwise_min(Cp[31] * tb, lim30);
            f32x2 A, B;
            A[0] = __builtin_amdgcn_exp2f(u2a[0]);
            A[1] = __builtin_amdgcn_exp2f(u2a[1]);
            B[0] = __builtin_amdgcn_exp2f(u2b[0]);
            B[1] = __builtin_amdgcn_exp2f(u2b[1]);
            A += 1.0f; B += 1.0f;
            f32x2 M = A * B;              // {A0B0, A1B1}
            float R = __builtin_amdgcn_rcpf(M[0] * M[1]);
            f32x2 RM; RM[0] = M[1] * R; RM[1] = M[0] * R;
            f32x2 sa = RM * B;            // {1/A0, 1/A1}
            f32x2 sb = RM * A;            // {1/B0, 1/B1}
            f32x2 pa = ta * sa;
            f32x2 pb = tb * sb;
            f32x2 acc = {bb3, 0.0f};
            acc = __builtin_elementwise_fma(pa, Cp[32], acc);
            acc = __builtin_elementwise_fma(pb, Cp[33], acc);
            res[r] = acc[0] + acc[1];
        }
        f32x4 ov = {res[0], res[1], res[2], res[3]};
        ((f32x4*)out)[tid] = ov;
    } else if (base < rows) {
        // tail (not hit for B = 8388608)
        const float* uw0  = C;
        const float* uw1  = C + 8;
        const float* ub   = C + 16;
        const float* w2f  = C + 24;
        const float* bb2  = C + 56;
        const float* ncl2 = C + 60;
        const float* aw2  = C + 64;
        for (long long rr = base; rr < rows; ++rr) {
            float x0 = x[rr * 2 + 0], x1 = x[rr * 2 + 1];
            float h[8];
#pragma unroll
            for (int j = 0; j < 8; ++j) {
                float uu = fmaf(x0, uw0[j], fmaf(x1, uw1[j], ub[j]));
                float s  = __builtin_amdgcn_rcpf(
                               1.0f + __builtin_amdgcn_exp2f(fminf(uu, 15.0f)));
                h[j] = uu * s;
            }
            float o = bb3;
#pragma unroll
            for (int k = 0; k < 4; ++k) {
                float t = bb2[k];
#pragma unroll
                for (int j = 0; j < 8; ++j) t = fmaf(h[j], w2f[j * 4 + k], t);
                float u2 = fminf(ncl2[k] * t, 30.0f);
                float sg = __builtin_amdgcn_rcpf(
                               1.0f + __builtin_amdgcn_exp2f(u2));
                o = fmaf(t * sg, aw2[k], o);
            }
            out[rr] = o;
        }
    }
}

extern "C" void kernel_launch(void* const* d_in, const int* in_sizes, int n_in,
                              void* d_out, int out_size, void* d_ws, size_t ws_size,
                              hipStream_t stream) {
    const float* x  = (const float*)d_in[0];
    const float* W1 = (const float*)d_in[1];
    const float* b1 = (const float*)d_in[2];
    const float* a1 = (const float*)d_in[3];
    const float* c1 = (const float*)d_in[4];
    const float* W2 = (const float*)d_in[5];
    const float* b2 = (const float*)d_in[6];
    const float* a2 = (const float*)d_in[7];
    const float* c2 = (const float*)d_in[8];
    const float* W3 = (const float*)d_in[9];
    const float* b3 = (const float*)d_in[10];
    float* out = (float*)d_out;
    float* C   = (float*)d_ws;

    prefold_kernel<<<1, 64, 0, stream>>>(W1, b1, a1, c1, W2, b2, a2, c2,
                                         W3, b3, C);

    int rows  = in_sizes[0] / 2;
    int rows4 = (rows + 3) / 4;            // 4 rows/thread, one-shot
    int block = 256;
    int grid  = (rows4 + block - 1) / block;

    PlaygroundModel_66365834658304_kernel<<<grid, block, 0, stream>>>(
        x, C, out, rows);
}

// Round 12
// 127.174 us; speedup vs baseline: 1.0368x; 1.0194x over previous
//
#include <hip/hip_runtime.h>

#define NLOG2E -1.44269504088896340736f

typedef float f32x2 __attribute__((ext_vector_type(2)));
typedef float f32x4 __attribute__((ext_vector_type(4)));

// K1: PARALLEL prefold — one folded constant per lane (69 lanes), all global
//     loads issued concurrently -> one latency round (~1-2 us) instead of the
//     previous 1-thread serial chain (~7 us).
// K2: r8's best-measured body: one-shot, 4 rows/thread, packed f32x2 math
//     (v_pk_fma_f32 et al.), constants via s_load->SGPR, plain rcp sigmoid.
//
// ws layout (floats): [0:8)=uw0 [8:16)=uw1 [16:24)=ub [24:56)=w2f
//                     [56:60)=b2 [60:64)=ncl2 [64:68)=aw2 [68]=bb3

__global__ void prefold_kernel(
    const float* __restrict__ W1, const float* __restrict__ b1,
    const float* __restrict__ a1, const float* __restrict__ c1,
    const float* __restrict__ W2, const float* __restrict__ b2,
    const float* __restrict__ a2, const float* __restrict__ c2,
    const float* __restrict__ W3, const float* __restrict__ b3,
    float* __restrict__ C)
{
    int i = threadIdx.x;
    if (i < 8) {                                   // uw0
        C[i] = W1[i] * (c1[i] * NLOG2E);
    } else if (i < 16) {                           // uw1
        int j = i - 8;
        C[i] = W1[8 + j] * (c1[j] * NLOG2E);
    } else if (i < 24) {                           // ub
        int j = i - 16;
        C[i] = b1[j] * (c1[j] * NLOG2E);
    } else if (i < 56) {                           // w2f
        int j = (i - 24) >> 2, k = (i - 24) & 3;
        C[i] = W2[j * 4 + k] * (a1[j] / (c1[j] * NLOG2E));
    } else if (i < 60) {                           // b2
        C[i] = b2[i - 56];
    } else if (i < 64) {                           // ncl2
        C[i] = c2[i - 60] * NLOG2E;
    } else if (i < 68) {                           // aw2
        C[i] = a2[i - 64] * W3[i - 64];
    } else if (i == 68) {                          // bb3
        C[i] = b3[0];
    }
}

__global__ __launch_bounds__(256, 4) void PlaygroundModel_66365834658304_kernel(
    const float* __restrict__ x, const float* __restrict__ C,
    float* __restrict__ out, int rows)
{
    const f32x2* Cp = (const f32x2*)C;
    // uw0 pairs: Cp[0..3]  uw1: Cp[4..7]  ub: Cp[8..11]
    // w2f pairs: Cp[12 + j*2 + kp]  b2: Cp[28..29]  ncl2: Cp[30..31]
    // aw2: Cp[32..33]  bb3: C[68]
    float bb3 = C[68];

    int tid = blockIdx.x * blockDim.x + threadIdx.x;
    long long base = (long long)tid * 4;

    if (base + 3 < rows) {
        const f32x4* x4 = (const f32x4*)x;
        f32x4 p0 = x4[(size_t)tid * 2 + 0];
        f32x4 p1 = x4[(size_t)tid * 2 + 1];
        float X0[4] = {p0.x, p0.z, p1.x, p1.z};
        float X1[4] = {p0.y, p0.w, p1.y, p1.w};

        // stage 1: u-values, 4 rows x 4 j-pairs of pk_fma
        f32x2 uv[4][4];
#pragma unroll
        for (int r = 0; r < 4; ++r) {
            f32x2 x0b = {X0[r], X0[r]};
            f32x2 x1b = {X1[r], X1[r]};
#pragma unroll
            for (int p = 0; p < 4; ++p)
                uv[r][p] = __builtin_elementwise_fma(
                               x0b, Cp[p],
                               __builtin_elementwise_fma(x1b, Cp[4 + p],
                                                         Cp[8 + p]));
        }

        // stage 2: h_eff = u * rcp(1 + exp2(u)); trans scalar, rest packed
#pragma unroll
        for (int r = 0; r < 4; ++r)
#pragma unroll
            for (int p = 0; p < 4; ++p) {
                f32x2 e;
                e[0] = __builtin_amdgcn_exp2f(uv[r][p][0]);
                e[1] = __builtin_amdgcn_exp2f(uv[r][p][1]);
                f32x2 d = e + 1.0f;
                f32x2 s;
                s[0] = __builtin_amdgcn_rcpf(d[0]);
                s[1] = __builtin_amdgcn_rcpf(d[1]);
                uv[r][p] *= s;             // h_eff in place
            }

        // stage 3: layer-2 dot-8, two k-pair accumulators per row
        float res[4];
#pragma unroll
        for (int r = 0; r < 4; ++r) {
            f32x2 ta = Cp[28], tb = Cp[29];
#pragma unroll
            for (int j = 0; j < 8; ++j) {
                float hj = uv[r][j >> 1][j & 1];
                f32x2 hb = {hj, hj};
                ta = __builtin_elementwise_fma(hb, Cp[12 + j * 2 + 0], ta);
                tb = __builtin_elementwise_fma(hb, Cp[12 + j * 2 + 1], tb);
            }
            // stage 4: second activation + final reduce
            f32x2 u2a = Cp[30] * ta;
            f32x2 u2b = Cp[31] * tb;
            f32x2 ea, eb;
            ea[0] = __builtin_amdgcn_exp2f(u2a[0]);
            ea[1] = __builtin_amdgcn_exp2f(u2a[1]);
            eb[0] = __builtin_amdgcn_exp2f(u2b[0]);
            eb[1] = __builtin_amdgcn_exp2f(u2b[1]);
            f32x2 da = ea + 1.0f, db = eb + 1.0f;
            f32x2 sa, sb;
            sa[0] = __builtin_amdgcn_rcpf(da[0]);
            sa[1] = __builtin_amdgcn_rcpf(da[1]);
            sb[0] = __builtin_amdgcn_rcpf(db[0]);
            sb[1] = __builtin_amdgcn_rcpf(db[1]);
            f32x2 pa = ta * sa;
            f32x2 pb = tb * sb;
            f32x2 acc = {bb3, 0.0f};
            acc = __builtin_elementwise_fma(pa, Cp[32], acc);
            acc = __builtin_elementwise_fma(pb, Cp[33], acc);
            res[r] = acc[0] + acc[1];
        }
        f32x4 ov = {res[0], res[1], res[2], res[3]};
        ((f32x4*)out)[tid] = ov;
    } else if (base < rows) {
        // tail (not hit for B = 8388608)
        const float* uw0  = C;
        const float* uw1  = C + 8;
        const float* ub   = C + 16;
        const float* w2f  = C + 24;
        const float* bb2  = C + 56;
        const float* ncl2 = C + 60;
        const float* aw2  = C + 64;
        for (long long rr = base; rr < rows; ++rr) {
            float x0 = x[rr * 2 + 0], x1 = x[rr * 2 + 1];
            float h[8];
#pragma unroll
            for (int j = 0; j < 8; ++j) {
                float uu = fmaf(x0, uw0[j], fmaf(x1, uw1[j], ub[j]));
                float s  = __builtin_amdgcn_rcpf(
                               1.0f + __builtin_amdgcn_exp2f(uu));
                h[j] = uu * s;
            }
            float o = bb3;
#pragma unroll
            for (int k = 0; k < 4; ++k) {
                float t = bb2[k];
#pragma unroll
                for (int j = 0; j < 8; ++j) t = fmaf(h[j], w2f[j * 4 + k], t);
                float u2 = ncl2[k] * t;
                float sg = __builtin_amdgcn_rcpf(
                               1.0f + __builtin_amdgcn_exp2f(u2));
                o = fmaf(t * sg, aw2[k], o);
            }
            out[rr] = o;
        }
    }
}

extern "C" void kernel_launch(void* const* d_in, const int* in_sizes, int n_in,
                              void* d_out, int out_size, void* d_ws, size_t ws_size,
                              hipStream_t stream) {
    const float* x  = (const float*)d_in[0];
    const float* W1 = (const float*)d_in[1];
    const float* b1 = (const float*)d_in[2];
    const float* a1 = (const float*)d_in[3];
    const float* c1 = (const float*)d_in[4];
    const float* W2 = (const float*)d_in[5];
    const float* b2 = (const float*)d_in[6];
    const float* a2 = (const float*)d_in[7];
    const float* c2 = (const float*)d_in[8];
    const float* W3 = (const float*)d_in[9];
    const float* b3 = (const float*)d_in[10];
    float* out = (float*)d_out;
    float* C   = (float*)d_ws;

    prefold_kernel<<<1, 128, 0, stream>>>(W1, b1, a1, c1, W2, b2, a2, c2,
                                          W3, b3, C);

    int rows  = in_sizes[0] / 2;
    int rows4 = (rows + 3) / 4;            // 4 rows/thread, one-shot
    int block = 256;
    int grid  = (rows4 + block - 1) / block;

    PlaygroundModel_66365834658304_kernel<<<grid, block, 0, stream>>>(
        x, C, out, rows);
}